// Round 5
// baseline (216.028 us; speedup 1.0000x reference)
//
#include <hip/hip_runtime.h>

#define NROWS 4096
#define DIM   1024

using f32x4 = __attribute__((ext_vector_type(4))) float;
using bfrag = __attribute__((ext_vector_type(8))) short;

__device__ __forceinline__ unsigned short f2bf(float f) {
  unsigned u = __float_as_uint(f);
  u += 0x7fffu + ((u >> 16) & 1u);
  return (unsigned short)(u >> 16);
}
__device__ __forceinline__ float bf2f(unsigned short b) {
  return __uint_as_float(((unsigned)b) << 16);
}
__device__ __forceinline__ unsigned long long shflx64(unsigned long long v, int m) {
  int lo = __shfl_xor((int)(unsigned)(v & 0xffffffffull), m);
  int hi = __shfl_xor((int)(unsigned)(v >> 32), m);
  return ((unsigned long long)(unsigned)hi << 32) | (unsigned)lo;
}

// fp32 -> bf16 (RNE) + row squared-norms + per-row stat init (init fused here)
__global__ void prep_kernel(const float* __restrict__ X, unsigned short* __restrict__ Xb,
                            float* __restrict__ sqv, int* maxS, int* maxD,
                            unsigned long long* minS, unsigned long long* minD,
                            float* out) {
  int row = blockIdx.x, t = threadIdx.x;  // 256 threads, 4 floats each
  float4 v = reinterpret_cast<const float4*>(X + (size_t)row * DIM)[t];
  unsigned short b0 = f2bf(v.x), b1 = f2bf(v.y), b2 = f2bf(v.z), b3 = f2bf(v.w);
  float f0 = bf2f(b0), f1 = bf2f(b1), f2 = bf2f(b2), f3 = bf2f(b3);
  float s = f0 * f0 + f1 * f1 + f2 * f2 + f3 * f3;
  reinterpret_cast<ushort4*>(Xb + (size_t)row * DIM)[t] = make_ushort4(b0, b1, b2, b3);
  for (int m = 32; m; m >>= 1) s += __shfl_xor(s, m);
  __shared__ float ws4[4];
  if ((t & 63) == 0) ws4[t >> 6] = s;
  __syncthreads();
  if (t == 0) {
    sqv[row] = (ws4[0] + ws4[1]) + (ws4[2] + ws4[3]);
    maxS[row] = 0; maxD[row] = 0; minS[row] = ~0ull; minD[row] = ~0ull;
    if (row == 0) out[0] = 0.f;
  }
}

// Stage one BK=64 tile pair into BASE (A at +0, B at +16K). R2-proven pattern:
// each global_load_lds covers 8 contiguous rows x 128B (coalesced); k-slot XOR
// involution (rule 21: linear LDS dest, inverse-swizzled global source).
#define STAGE(BASE, KS)                                                          \
  {                                                                              \
    _Pragma("unroll")                                                            \
    for (int qq = 0; qq < 4; ++qq) {                                             \
      int boff = (wave * 4 + qq) * 1024;            /* 8 rows of 128B */         \
      int r = (wave * 4 + qq) * 8 + (lane >> 3);    /* row this lane fills */    \
      const unsigned short* sA = Xb + (size_t)(row0 + r) * DIM + (KS) + ksrc;    \
      __builtin_amdgcn_global_load_lds(                                          \
          (const __attribute__((address_space(1))) void*)sA,                     \
          (__attribute__((address_space(3))) void*)((BASE) + boff), 16, 0, 0);   \
      const unsigned short* sB = Xb + (size_t)(col0 + r) * DIM + (KS) + ksrc;    \
      __builtin_amdgcn_global_load_lds(                                          \
          (const __attribute__((address_space(1))) void*)sB,                     \
          (__attribute__((address_space(3))) void*)((BASE) + 16384 + boff), 16, 0, 0); \
    }                                                                            \
  }

// One BK=64 compute step from BASE: 16 ds_read_b128 (swizzle-> ~2-way, free)
// + 32 MFMA. A/B share the identical lane->k map (Gram-safe).
#define BODY(BASE)                                                              \
  {                                                                             \
    unsigned short(*As_)[64] = (unsigned short(*)[64])(BASE);                   \
    unsigned short(*Bs_)[64] = (unsigned short(*)[64])((BASE) + 16384);         \
    _Pragma("unroll") for (int kk = 0; kk < 2; ++kk) {                          \
      bfrag a[4], b[4];                                                         \
      int kel = ((kk * 4 + q) ^ (lane & 7)) * 8;                                \
      _Pragma("unroll") for (int m = 0; m < 4; ++m)                             \
        a[m] = *(const bfrag*)&As_[wr + m * 16 + li][kel];                      \
      _Pragma("unroll") for (int n = 0; n < 4; ++n)                             \
        b[n] = *(const bfrag*)&Bs_[wc + n * 16 + li][kel];                      \
      _Pragma("unroll") for (int m = 0; m < 4; ++m)                             \
        _Pragma("unroll") for (int n = 0; n < 4; ++n)                           \
          acc[m][n] = __builtin_amdgcn_mfma_f32_16x16x32_bf16(a[m], b[n], acc[m][n], 0, 0, 0); \
    }                                                                           \
  }

// 128x128 bf16-MFMA Gram tile (triangular tn-major grid, XCD-chunked), BK=64
// double-buffered 2-phase (one barrier per K-step) + fused masked reductions.
__global__ __launch_bounds__(256) void gram_kernel(
    const unsigned short* __restrict__ Xb, const float* __restrict__ sqv,
    const int* __restrict__ tg, const int* __restrict__ fl,
    int* maxS, int* maxD, unsigned long long* minS, unsigned long long* minD) {
  __shared__ __attribute__((aligned(16))) char smem[65536];  // 2x(A16K|B16K); Ds alias
  __shared__ float srow[128], scol[128];
  __shared__ int rtagp[128], ctagp[128];

  // XCD-chunked bijective remap (528 = 8*66), then tn-major triangular decode:
  // consecutive logical g share the tn B-panel -> per-XCD L2 locality.
  int g = (blockIdx.x & 7) * 66 + (blockIdx.x >> 3);
  int tn = (int)((sqrtf(8.f * g + 1.f) - 1.f) * 0.5f);
  while ((tn + 1) * (tn + 2) / 2 <= g) ++tn;
  while (tn * (tn + 1) / 2 > g) --tn;
  int tm = g - tn * (tn + 1) / 2;  // 0 <= tm <= tn
  const int row0 = tm * 128, col0 = tn * 128;
  const int tid = threadIdx.x;
  const int wave = tid >> 6, lane = tid & 63;
  const int q = lane >> 4, li = lane & 15;
  const int ksrc = ((lane & 7) ^ (lane >> 3)) * 8;  // staging source k-offset

  char* B0 = smem;           // buf0: A 16K | B 16K
  char* B1 = smem + 32768;   // buf1: A 16K | B 16K
  float* Ds = (float*)smem;  // 64x128 f32 half-tile, aliased after K-loop

  f32x4 acc[4][4] = {};
  const int wr = (wave >> 1) * 64, wc = (wave & 1) * 64;

  STAGE(B0, 0);
  if (tid < 128) {
    srow[tid] = sqv[row0 + tid];
    rtagp[tid] = (fl[row0 + tid] << 12) | tg[row0 + tid];  // tg<1024, fl in {0,1}
  } else {
    int c = tid - 128;
    scol[c] = sqv[col0 + c];
    ctagp[c] = (fl[col0 + c] << 12) | tg[col0 + c];
  }
  __syncthreads();  // buf0 staged
  for (int tt = 0; tt < 16; tt += 2) {
    STAGE(B1, (tt + 1) * 64);        // prefetch odd step under even compute
    BODY(B0);
    __syncthreads();                  // drains lgkm (B0 reads) + vmcnt (B1 staged)
    if (tt < 14) STAGE(B0, (tt + 2) * 64);
    BODY(B1);
    __syncthreads();
  }

  // epilogue: dist into Ds per 64-row half; column-direction partials in-reg
  // (locally scoped per half), row scans from LDS.
#pragma unroll
  for (int h = 0; h < 2; ++h) {
    if ((wave >> 1) == h) {  // writer waves for this half (no barriers inside)
      float cmxS[4], cmxD[4];
      unsigned long long cmnS[4], cmnD[4];
      int ctv[4]; float scv[4];
#pragma unroll
      for (int n = 0; n < 4; ++n) {
        cmxS[n] = -1.f; cmxD[n] = -1.f; cmnS[n] = ~0ull; cmnD[n] = ~0ull;
        int lc = wc + n * 16 + li; ctv[n] = ctagp[lc]; scv[n] = scol[lc];
      }
#pragma unroll
      for (int m = 0; m < 4; ++m)
#pragma unroll
        for (int r = 0; r < 4; ++r) {
          int lr = wr + m * 16 + q * 4 + r;   // C/D layout (m89-verified)
          int rl = lr & 63;
          int rt = rtagp[lr];
          float sr = srow[lr];
          unsigned long long rbase = (unsigned)(row0 + lr);
#pragma unroll
          for (int n = 0; n < 4; ++n) {
            float d = sqrtf(fmaxf(sr + scv[n] - 2.0f * acc[m][n][r], 1e-12f));
            Ds[rl * 128 + ((wc + n * 16 + li) ^ (rl & 31))] = d;
            int x = rt ^ ctv[n];
            unsigned long long pk = ((unsigned long long)__float_as_uint(d) << 32) | rbase;
            if ((x & 0xFFF) == 0) {
              if ((x >> 12) == 0) cmxS[n] = fmaxf(cmxS[n], d);
              else                cmxD[n] = fmaxf(cmxD[n], d);
            } else {
              if ((x >> 12) == 0) { if (pk < cmnS[n]) cmnS[n] = pk; }
              else                { if (pk < cmnD[n]) cmnD[n] = pk; }
            }
          }
        }
      // reduce col partials over q (lanes sharing li) and commit (atomics merge)
#pragma unroll
      for (int n = 0; n < 4; ++n) {
        cmxS[n] = fmaxf(cmxS[n], __shfl_xor(cmxS[n], 16));
        cmxD[n] = fmaxf(cmxD[n], __shfl_xor(cmxD[n], 16));
        unsigned long long o = shflx64(cmnS[n], 16); if (o < cmnS[n]) cmnS[n] = o;
        o = shflx64(cmnD[n], 16); if (o < cmnD[n]) cmnD[n] = o;
        cmxS[n] = fmaxf(cmxS[n], __shfl_xor(cmxS[n], 32));
        cmxD[n] = fmaxf(cmxD[n], __shfl_xor(cmxD[n], 32));
        o = shflx64(cmnS[n], 32); if (o < cmnS[n]) cmnS[n] = o;
        o = shflx64(cmnD[n], 32); if (o < cmnD[n]) cmnD[n] = o;
        if (lane < 16) {
          int gc = col0 + wc + n * 16 + lane;
          atomicMax(&maxS[gc], __float_as_int(cmxS[n]));
          atomicMax(&maxD[gc], __float_as_int(cmxD[n]));
          atomicMin(&minS[gc], cmnS[n]);
          atomicMin(&minD[gc], cmnD[n]);
        }
      }
    }
    __syncthreads();  // Ds half visible to all
    // row scan: 64 rows x 128 cols; 4 threads/row (2 col-chunks x 2 wave-groups)
    {
      int rl = (wave & 1) * 32 + (lane & 31);
      int j = (wave >> 1) * 2 + (lane >> 5);
      int rt = rtagp[h * 64 + rl];
      float mxS = -1.f, mxD = -1.f;
      unsigned long long mnS = ~0ull, mnD = ~0ull;
      for (int i = 0; i < 32; ++i) {
        int c = j * 32 + i;
        float d = Ds[rl * 128 + (c ^ (rl & 31))];  // bank = i^(rl&31): conflict-free
        int x = rt ^ ctagp[c];
        unsigned long long pk =
            ((unsigned long long)__float_as_uint(d) << 32) | (unsigned)(col0 + c);
        if ((x & 0xFFF) == 0) { if ((x >> 12) == 0) mxS = fmaxf(mxS, d); else mxD = fmaxf(mxD, d); }
        else { if ((x >> 12) == 0) { if (pk < mnS) mnS = pk; } else { if (pk < mnD) mnD = pk; } }
      }
      mxS = fmaxf(mxS, __shfl_xor(mxS, 32));
      mxD = fmaxf(mxD, __shfl_xor(mxD, 32));
      unsigned long long o = shflx64(mnS, 32); if (o < mnS) mnS = o;
      o = shflx64(mnD, 32); if (o < mnD) mnD = o;
      if (lane < 32) {
        int gr = row0 + h * 64 + rl;
        atomicMax(&maxS[gr], __float_as_int(mxS));
        atomicMax(&maxD[gr], __float_as_int(mxD));
        atomicMin(&minS[gr], mnS);
        atomicMin(&minD[gr], mnD);
      }
    }
    __syncthreads();  // scans done before next half's writers overwrite Ds
  }
}

// per-row: recompute dist[same_min_idx, dif_min_idx], accumulate the three relu
// means. 128 blocks x 32 rows; ONE same-address atomicAdd per block (G12).
__global__ void finish_kernel(const unsigned short* __restrict__ Xb,
                              const float* __restrict__ sqv,
                              const int* __restrict__ maxS, const int* __restrict__ maxD,
                              const unsigned long long* __restrict__ minS,
                              const unsigned long long* __restrict__ minD, float* out) {
  int wave = threadIdx.x >> 6, lane = threadIdx.x & 63;
  float part = 0.f;
  for (int rr = 0; rr < 8; ++rr) {
    int row = blockIdx.x * 32 + wave * 8 + rr;
    unsigned long long pS = minS[row], pD = minD[row];
    int ia = (int)(pS & 0xffffffffull);  // same_min_idx (row of gather)
    int ib = (int)(pD & 0xffffffffull);  // dif_min_idx  (col of gather)
    const ushort4* pa = (const ushort4*)(Xb + (size_t)ia * DIM);
    const ushort4* pb = (const ushort4*)(Xb + (size_t)ib * DIM);
    float s = 0.f;
#pragma unroll
    for (int qq = 0; qq < 4; ++qq) {
      ushort4 a = pa[lane + qq * 64], b = pb[lane + qq * 64];
      s += bf2f(a.x) * bf2f(b.x) + bf2f(a.y) * bf2f(b.y) +
           bf2f(a.z) * bf2f(b.z) + bf2f(a.w) * bf2f(b.w);
    }
    for (int m = 32; m; m >>= 1) s += __shfl_xor(s, m);
    if (lane == 0) {
      float dneg = sqrtf(fmaxf(sqv[ia] + sqv[ib] - 2.f * s, 1e-12f));
      float mS = __int_as_float(maxS[row]);
      float mD = __int_as_float(maxD[row]);
      float mnSv = __uint_as_float((unsigned)(pS >> 32));
      float mnDv = __uint_as_float((unsigned)(pD >> 32));
      part += fmaxf(mS - mnSv + 0.8f, 0.f) + fmaxf(mD - mnDv + 0.5f, 0.f) +
              fmaxf(mS - dneg + 0.3f, 0.f);
    }
  }
  __shared__ float wp[4];
  if (lane == 0) wp[wave] = part;
  __syncthreads();
  if (threadIdx.x == 0)
    atomicAdd(out, ((wp[0] + wp[1]) + (wp[2] + wp[3])) * (1.0f / 4096.0f));
}

extern "C" void kernel_launch(void* const* d_in, const int* in_sizes, int n_in,
                              void* d_out, int out_size, void* d_ws, size_t ws_size,
                              hipStream_t stream) {
  const float* X = (const float*)d_in[0];
  const int* tg  = (const int*)d_in[1];
  const int* fl  = (const int*)d_in[2];
  float* out = (float*)d_out;

  // workspace layout (8.5 MB total)
  char* w = (char*)d_ws;
  unsigned short* Xb = (unsigned short*)(w);                    // 8,388,608 B
  float* sqv = (float*)(w + 8388608);                           //    16,384 B
  int* maxS  = (int*)(w + 8404992);                             //    16,384 B
  int* maxD  = (int*)(w + 8421376);                             //    16,384 B
  unsigned long long* minS = (unsigned long long*)(w + 8437760);//    32,768 B
  unsigned long long* minD = (unsigned long long*)(w + 8470528);//    32,768 B

  prep_kernel<<<NROWS, 256, 0, stream>>>(X, Xb, sqv, maxS, maxD, minS, minD, out);
  gram_kernel<<<528, 256, 0, stream>>>(Xb, sqv, tg, fl, maxS, maxD, minS, minD);
  finish_kernel<<<128, 256, 0, stream>>>(Xb, sqv, maxS, maxD, minS, minD, out);
}

// Round 6
// 149.549 us; speedup vs baseline: 1.4445x; 1.4445x over previous
//
#include <hip/hip_runtime.h>

#define NROWS 4096
#define DIM   1024

using f32x4 = __attribute__((ext_vector_type(4))) float;
using bfrag = __attribute__((ext_vector_type(8))) short;

__device__ __forceinline__ unsigned short f2bf(float f) {
  unsigned u = __float_as_uint(f);
  u += 0x7fffu + ((u >> 16) & 1u);
  return (unsigned short)(u >> 16);
}
__device__ __forceinline__ float bf2f(unsigned short b) {
  return __uint_as_float(((unsigned)b) << 16);
}
__device__ __forceinline__ unsigned long long shflx64(unsigned long long v, int m) {
  int lo = __shfl_xor((int)(unsigned)(v & 0xffffffffull), m);
  int hi = __shfl_xor((int)(unsigned)(v >> 32), m);
  return ((unsigned long long)(unsigned)hi << 32) | (unsigned)lo;
}

// fp32 -> bf16 (RNE) + row squared-norms + per-row stat init (init fused here)
__global__ void prep_kernel(const float* __restrict__ X, unsigned short* __restrict__ Xb,
                            float* __restrict__ sqv, int* maxS, int* maxD,
                            unsigned long long* minS, unsigned long long* minD,
                            float* out) {
  int row = blockIdx.x, t = threadIdx.x;  // 256 threads, 4 floats each
  float4 v = reinterpret_cast<const float4*>(X + (size_t)row * DIM)[t];
  unsigned short b0 = f2bf(v.x), b1 = f2bf(v.y), b2 = f2bf(v.z), b3 = f2bf(v.w);
  float f0 = bf2f(b0), f1 = bf2f(b1), f2 = bf2f(b2), f3 = bf2f(b3);
  float s = f0 * f0 + f1 * f1 + f2 * f2 + f3 * f3;
  reinterpret_cast<ushort4*>(Xb + (size_t)row * DIM)[t] = make_ushort4(b0, b1, b2, b3);
  for (int m = 32; m; m >>= 1) s += __shfl_xor(s, m);
  __shared__ float ws4[4];
  if ((t & 63) == 0) ws4[t >> 6] = s;
  __syncthreads();
  if (t == 0) {
    sqv[row] = (ws4[0] + ws4[1]) + (ws4[2] + ws4[3]);
    maxS[row] = 0; maxD[row] = 0; minS[row] = ~0ull; minD[row] = ~0ull;
    if (row == 0) out[0] = 0.f;
  }
}

// Stage one BK=64 tile pair (A at smem, B at smem+16K). R2-proven pattern:
// each global_load_lds covers 8 contiguous rows x 128B (coalesced); k-slot XOR
// involution (rule 21: linear LDS dest, inverse-swizzled global source).
#define STAGE(KS)                                                                \
  {                                                                              \
    _Pragma("unroll")                                                            \
    for (int qq = 0; qq < 4; ++qq) {                                             \
      int boff = (wave * 4 + qq) * 1024;            /* 8 rows of 128B */         \
      int r = (wave * 4 + qq) * 8 + (lane >> 3);    /* row this lane fills */    \
      const unsigned short* sA = Xb + (size_t)(row0 + r) * DIM + (KS) + ksrc;    \
      __builtin_amdgcn_global_load_lds(                                          \
          (const __attribute__((address_space(1))) void*)sA,                     \
          (__attribute__((address_space(3))) void*)(smem + boff), 16, 0, 0);     \
      const unsigned short* sB = Xb + (size_t)(col0 + r) * DIM + (KS) + ksrc;    \
      __builtin_amdgcn_global_load_lds(                                          \
          (const __attribute__((address_space(1))) void*)sB,                     \
          (__attribute__((address_space(3))) void*)(smem + 16384 + boff), 16, 0, 0); \
    }                                                                            \
  }

// 128x128 bf16-MFMA Gram tile (triangular tm-major grid) + fused masked
// reductions, fully in-register epilogue (no Ds tile). LDS ~35KB -> 4 blk/CU.
__global__ __launch_bounds__(256) void gram_kernel(
    const unsigned short* __restrict__ Xb, const float* __restrict__ sqv,
    const int* __restrict__ tg, const int* __restrict__ fl,
    int* maxS, int* maxD, unsigned long long* minS, unsigned long long* minD) {
  __shared__ __attribute__((aligned(16))) char smem[32768];  // A 16K | B 16K
  __shared__ float srow[128], scol[128];
  __shared__ int rtagp[128], ctagp[128];

  // triangular decode (R2-proven): tiles with tm <= tn
  int tm = 0, g = blockIdx.x, rem = 32;
  while (g >= rem) { g -= rem; rem--; tm++; }
  int tn = tm + g;
  const int row0 = tm * 128, col0 = tn * 128;
  const int tid = threadIdx.x;
  const int wave = tid >> 6, lane = tid & 63;
  const int q = lane >> 4, li = lane & 15;
  const int ksrc = ((lane & 7) ^ (lane >> 3)) * 8;  // staging source k-offset

  if (tid < 128) {
    srow[tid] = sqv[row0 + tid];
    rtagp[tid] = (fl[row0 + tid] << 12) | tg[row0 + tid];  // tg<1024, fl in {0,1}
  } else {
    int c = tid - 128;
    scol[c] = sqv[col0 + c];
    ctagp[c] = (fl[col0 + c] << 12) | tg[col0 + c];
  }

  unsigned short (*As)[64] = (unsigned short (*)[64])smem;
  unsigned short (*Bs)[64] = (unsigned short (*)[64])(smem + 16384);

  f32x4 acc[4][4] = {};
  const int wr = (wave >> 1) * 64, wc = (wave & 1) * 64;

  for (int ks = 0; ks < DIM; ks += 64) {
    __syncthreads();  // previous tile fully consumed (also orders tag fills)
    STAGE(ks);
    __syncthreads();  // staging complete
#pragma unroll
    for (int kk = 0; kk < 2; ++kk) {
      bfrag a[4], b[4];
      int kel = ((kk * 4 + q) ^ (lane & 7)) * 8;  // same k-map for A and B -> Gram safe
#pragma unroll
      for (int m = 0; m < 4; ++m)
        a[m] = *(const bfrag*)&As[wr + m * 16 + li][kel];
#pragma unroll
      for (int n = 0; n < 4; ++n)
        b[n] = *(const bfrag*)&Bs[wc + n * 16 + li][kel];
#pragma unroll
      for (int m = 0; m < 4; ++m)
#pragma unroll
        for (int n = 0; n < 4; ++n)
          acc[m][n] = __builtin_amdgcn_mfma_f32_16x16x32_bf16(a[m], b[n], acc[m][n], 0, 0, 0);
    }
  }

  // ---- fully in-register epilogue: no LDS tile, no barriers ----
  // lane (q,li) holds element (row = wr+m*16+q*4+r, col = wc+n*16+li).
  // Row stats: reduce over n in-lane + li via shfl_xor 1/2/4/8.
  // Col stats: reduce over (m,r) in-lane + q via shfl_xor 16/32.
  float cmxS[4], cmxD[4];
  unsigned long long cmnS[4], cmnD[4];
  int ctv[4]; float scv[4];
#pragma unroll
  for (int n = 0; n < 4; ++n) {
    cmxS[n] = -1.f; cmxD[n] = -1.f; cmnS[n] = ~0ull; cmnD[n] = ~0ull;
    int lc = wc + n * 16 + li; ctv[n] = ctagp[lc]; scv[n] = scol[lc];
  }
#pragma unroll
  for (int m = 0; m < 4; ++m)
#pragma unroll
    for (int r = 0; r < 4; ++r) {
      int lr = wr + m * 16 + q * 4 + r;   // C/D layout (m89-verified)
      int rt = rtagp[lr];
      float sr = srow[lr];
      unsigned long long rbase = (unsigned)(row0 + lr);
      float rmxS = -1.f, rmxD = -1.f;
      unsigned long long rmnS = ~0ull, rmnD = ~0ull;
#pragma unroll
      for (int n = 0; n < 4; ++n) {
        float d = sqrtf(fmaxf(sr + scv[n] - 2.0f * acc[m][n][r], 1e-12f));
        int x = rt ^ ctv[n];
        unsigned long long db = (unsigned long long)__float_as_uint(d) << 32;
        unsigned long long pkr = db | (unsigned)(col0 + wc + n * 16 + li);
        unsigned long long pkc = db | rbase;
        if ((x & 0xFFF) == 0) {
          if ((x >> 12) == 0) { rmxS = fmaxf(rmxS, d); cmxS[n] = fmaxf(cmxS[n], d); }
          else                { rmxD = fmaxf(rmxD, d); cmxD[n] = fmaxf(cmxD[n], d); }
        } else {
          if ((x >> 12) == 0) { if (pkr < rmnS) rmnS = pkr; if (pkc < cmnS[n]) cmnS[n] = pkc; }
          else                { if (pkr < rmnD) rmnD = pkr; if (pkc < cmnD[n]) cmnD[n] = pkc; }
        }
      }
#pragma unroll
      for (int mk = 1; mk <= 8; mk <<= 1) {
        rmxS = fmaxf(rmxS, __shfl_xor(rmxS, mk));
        rmxD = fmaxf(rmxD, __shfl_xor(rmxD, mk));
        unsigned long long o = shflx64(rmnS, mk); if (o < rmnS) rmnS = o;
        o = shflx64(rmnD, mk); if (o < rmnD) rmnD = o;
      }
      if (li == 0) {
        int gr = row0 + lr;
        atomicMax(&maxS[gr], __float_as_int(rmxS));
        atomicMax(&maxD[gr], __float_as_int(rmxD));
        atomicMin(&minS[gr], rmnS);
        atomicMin(&minD[gr], rmnD);
      }
    }
#pragma unroll
  for (int n = 0; n < 4; ++n) {
#pragma unroll
    for (int mk = 16; mk <= 32; mk <<= 1) {
      cmxS[n] = fmaxf(cmxS[n], __shfl_xor(cmxS[n], mk));
      cmxD[n] = fmaxf(cmxD[n], __shfl_xor(cmxD[n], mk));
      unsigned long long o = shflx64(cmnS[n], mk); if (o < cmnS[n]) cmnS[n] = o;
      o = shflx64(cmnD[n], mk); if (o < cmnD[n]) cmnD[n] = o;
    }
    if (lane < 16) {
      int gc = col0 + wc + n * 16 + lane;
      atomicMax(&maxS[gc], __float_as_int(cmxS[n]));
      atomicMax(&maxD[gc], __float_as_int(cmxD[n]));
      atomicMin(&minS[gc], cmnS[n]);
      atomicMin(&minD[gc], cmnD[n]);
    }
  }
}

// per-row: recompute dist[same_min_idx, dif_min_idx], accumulate the three relu
// means. 128 blocks x 32 rows; ONE same-address atomicAdd per block (G12).
__global__ void finish_kernel(const unsigned short* __restrict__ Xb,
                              const float* __restrict__ sqv,
                              const int* __restrict__ maxS, const int* __restrict__ maxD,
                              const unsigned long long* __restrict__ minS,
                              const unsigned long long* __restrict__ minD, float* out) {
  int wave = threadIdx.x >> 6, lane = threadIdx.x & 63;
  float part = 0.f;
  for (int rr = 0; rr < 8; ++rr) {
    int row = blockIdx.x * 32 + wave * 8 + rr;
    unsigned long long pS = minS[row], pD = minD[row];
    int ia = (int)(pS & 0xffffffffull);  // same_min_idx (row of gather)
    int ib = (int)(pD & 0xffffffffull);  // dif_min_idx  (col of gather)
    const ushort4* pa = (const ushort4*)(Xb + (size_t)ia * DIM);
    const ushort4* pb = (const ushort4*)(Xb + (size_t)ib * DIM);
    float s = 0.f;
#pragma unroll
    for (int qq = 0; qq < 4; ++qq) {
      ushort4 a = pa[lane + qq * 64], b = pb[lane + qq * 64];
      s += bf2f(a.x) * bf2f(b.x) + bf2f(a.y) * bf2f(b.y) +
           bf2f(a.z) * bf2f(b.z) + bf2f(a.w) * bf2f(b.w);
    }
    for (int m = 32; m; m >>= 1) s += __shfl_xor(s, m);
    if (lane == 0) {
      float dneg = sqrtf(fmaxf(sqv[ia] + sqv[ib] - 2.f * s, 1e-12f));
      float mS = __int_as_float(maxS[row]);
      float mD = __int_as_float(maxD[row]);
      float mnSv = __uint_as_float((unsigned)(pS >> 32));
      float mnDv = __uint_as_float((unsigned)(pD >> 32));
      part += fmaxf(mS - mnSv + 0.8f, 0.f) + fmaxf(mD - mnDv + 0.5f, 0.f) +
              fmaxf(mS - dneg + 0.3f, 0.f);
    }
  }
  __shared__ float wp[4];
  if (lane == 0) wp[wave] = part;
  __syncthreads();
  if (threadIdx.x == 0)
    atomicAdd(out, ((wp[0] + wp[1]) + (wp[2] + wp[3])) * (1.0f / 4096.0f));
}

extern "C" void kernel_launch(void* const* d_in, const int* in_sizes, int n_in,
                              void* d_out, int out_size, void* d_ws, size_t ws_size,
                              hipStream_t stream) {
  const float* X = (const float*)d_in[0];
  const int* tg  = (const int*)d_in[1];
  const int* fl  = (const int*)d_in[2];
  float* out = (float*)d_out;

  // workspace layout (8.5 MB total)
  char* w = (char*)d_ws;
  unsigned short* Xb = (unsigned short*)(w);                    // 8,388,608 B
  float* sqv = (float*)(w + 8388608);                           //    16,384 B
  int* maxS  = (int*)(w + 8404992);                             //    16,384 B
  int* maxD  = (int*)(w + 8421376);                             //    16,384 B
  unsigned long long* minS = (unsigned long long*)(w + 8437760);//    32,768 B
  unsigned long long* minD = (unsigned long long*)(w + 8470528);//    32,768 B

  prep_kernel<<<NROWS, 256, 0, stream>>>(X, Xb, sqv, maxS, maxD, minS, minD, out);
  gram_kernel<<<528, 256, 0, stream>>>(Xb, sqv, tg, fl, maxS, maxD, minS, minD);
  finish_kernel<<<128, 256, 0, stream>>>(Xb, sqv, maxS, maxD, minS, minD, out);
}